// Round 3
// baseline (1284.670 us; speedup 1.0000x reference)
//
#include <hip/hip_runtime.h>
#include <hip/hip_bf16.h>

// Problem constants (DeepSeek-V2-style scaled config)
#define S 2048
#define D 1024
#define H 16
#define DH 64
#define LAYERS 2
#define E 8
#define I_DIM 512
#define SI 1024
#define V 32000
#define NSTRIP 125   // V / 256

typedef unsigned short ushort_t;
typedef __attribute__((ext_vector_type(8))) short short8;   // 8 bf16 (4 VGPRs)
typedef __attribute__((ext_vector_type(4))) float floatx4;  // MFMA accumulator

__device__ __forceinline__ float bf2f(ushort_t u) {
  union { unsigned i; float f; } x;
  x.i = ((unsigned)u) << 16;
  return x.f;
}
__device__ __forceinline__ ushort_t f2bf(float f) {
  union { float f; unsigned u; } x; x.f = f;
  unsigned r = x.u + 0x7FFFu + ((x.u >> 16) & 1u);
  return (ushort_t)(r >> 16);
}
__device__ __forceinline__ int pack2(float a, float b) {
  return (int)((unsigned)f2bf(a) | ((unsigned)f2bf(b) << 16));
}

// Bijective XCD-aware block-id swizzle (T1, m204 form). Blocks that land on
// the same XCD (hw round-robin by original id) get CONTIGUOUS swizzled ids,
// so decomposing sw weight-panel-fastest gives per-XCD L2 reuse of weights.
__device__ __forceinline__ int xcd_swz(int bid, int nwg) {
  int q = nwg >> 3, r = nwg & 7;
  int x = bid & 7, o = bid >> 3;
  return (x < r ? x * (q + 1) : r * (q + 1) + (x - r) * q) + o;
}

// async global->LDS, 16 B per lane; LDS dst = wave-uniform base + lane*16
__device__ __forceinline__ void gl_lds16(const ushort_t* g, ushort_t* l) {
  __builtin_amdgcn_global_load_lds((const __attribute__((address_space(1))) void*)g,
                                   (__attribute__((address_space(3))) void*)l, 16, 0, 0);
}

// ---------------------------------------------------------------------------
__global__ __launch_bounds__(256) void convert_k(const float* __restrict__ in,
                                                 ushort_t* __restrict__ out, int n8) {
  int i = blockIdx.x * 256 + threadIdx.x;
  if (i >= n8) return;
  const float4* p = (const float4*)in + (size_t)i * 2;
  float4 a = p[0], b = p[1];
  int4 pk = {pack2(a.x, a.y), pack2(a.z, a.w), pack2(b.x, b.y), pack2(b.z, b.w)};
  ((int4*)out)[i] = pk;
}

__global__ __launch_bounds__(256) void embed_k(const int* __restrict__ tok,
                                               const float* __restrict__ emb,
                                               float* __restrict__ h) {
  int idx = blockIdx.x * 256 + threadIdx.x;
  if (idx >= S * D / 4) return;
  int s = idx >> 8;
  int d4 = idx & 255;
  int t = tok[s];
  float4 u = *(const float4*)(emb + (size_t)t * D + d4 * 4);
  *(float4*)(h + (size_t)s * D + d4 * 4) = u;
}

__global__ __launch_bounds__(256) void rmsnorm_k(const float* __restrict__ h,
                                                 const float* __restrict__ w,
                                                 ushort_t* __restrict__ xb) {
  int s = blockIdx.x, tid = threadIdx.x;
  __shared__ float red[256];
  float4 hv = *(const float4*)(h + (size_t)s * D + tid * 4);
  red[tid] = hv.x * hv.x + hv.y * hv.y + hv.z * hv.z + hv.w * hv.w;
  __syncthreads();
  for (int st = 128; st > 0; st >>= 1) {
    if (tid < st) red[tid] += red[tid + st];
    __syncthreads();
  }
  float inv = rsqrtf(red[0] * (1.0f / 1024.0f) + 1e-6f);
  float4 wv = *(const float4*)(w + tid * 4);
  int2 pk;
  pk.x = pack2(hv.x * inv * wv.x, hv.y * inv * wv.y);
  pk.y = pack2(hv.z * inv * wv.z, hv.w * inv * wv.w);
  *(int2*)(xb + (size_t)s * D + tid * 4) = pk;
}

// ---------------------------------------------------------------------------
// MFMA GEMM (m97 structure): C[M,N] = A[M,K](bf16) @ B[N,K](bf16)^T
// Tile TM x TN, BK=32, 4 waves (2x2), 16x16x32 bf16 MFMA, async LDS staging.
// MODE 0: f32 store; 1: bf16 store; 2: f32 accumulate. EXPERT: B = [E][D][I].
// XCD-swizzled, weight-panel-fastest decomposition (same-XCD blocks share B).
// ---------------------------------------------------------------------------
template <int TM, int TN, int MODE, int EXPERT>
__global__ __launch_bounds__(256) void gbt_k(const ushort_t* __restrict__ A, int lda,
                                             const ushort_t* __restrict__ B, int ldb,
                                             void* __restrict__ Cv, int ldc, int K) {
  constexpr int WM = TM / 2, WN = TN / 2;
  constexpr int MT = WM / 16, NT = WN / 16;
  constexpr int CA = TM / 16, CB = TN / 16;
  __shared__ __align__(16) ushort_t As[TM * 32];
  __shared__ __align__(16) ushort_t Bs[TN * 32];
  int tid = threadIdx.x;
  int nwg = gridDim.x * gridDim.y;
  int sw = xcd_swz(blockIdx.x + gridDim.x * blockIdx.y, nwg);
  int bx = sw / gridDim.y, by = sw % gridDim.y;   // y-fastest: share B panel
  int n0 = bx * TN, m0 = by * TM;
  int w = tid >> 6, lane = tid & 63, quad = lane >> 4, l16 = lane & 15;
  int wm = (w >> 1) * WM, wn = (w & 1) * WN;
  int srow = lane >> 2, sko = (lane & 3) * 8;

  floatx4 acc[MT][NT];
#pragma unroll
  for (int mi = 0; mi < MT; mi++)
#pragma unroll
    for (int ni = 0; ni < NT; ni++)
      acc[mi][ni] = (floatx4){0.f, 0.f, 0.f, 0.f};

  for (int k0 = 0; k0 < K; k0 += 32) {
#pragma unroll
    for (int c = 0; c < CA; c += 4) {
      int ch = c + w;
      const ushort_t* gp = A + (size_t)(m0 + ch * 16 + srow) * lda + k0 + sko;
      gl_lds16(gp, As + ch * 512);
    }
#pragma unroll
    for (int c = 0; c < CB; c += 4) {
      int ch = c + w;
      const ushort_t* gp;
      if (EXPERT) {
        int kk = k0 + sko;
        int e = kk >> 9;
        gp = B + ((size_t)(e * D + n0 + ch * 16 + srow)) * I_DIM + (kk & 511);
      } else {
        gp = B + (size_t)(n0 + ch * 16 + srow) * ldb + k0 + sko;
      }
      gl_lds16(gp, Bs + ch * 512);
    }
    __syncthreads();
    short8 af[MT], bfv[NT];
#pragma unroll
    for (int mi = 0; mi < MT; mi++)
      af[mi] = *(const short8*)(As + (wm + mi * 16 + l16) * 32 + quad * 8);
#pragma unroll
    for (int ni = 0; ni < NT; ni++)
      bfv[ni] = *(const short8*)(Bs + (wn + ni * 16 + l16) * 32 + quad * 8);
#pragma unroll
    for (int mi = 0; mi < MT; mi++)
#pragma unroll
      for (int ni = 0; ni < NT; ni++)
        acc[mi][ni] = __builtin_amdgcn_mfma_f32_16x16x32_bf16(af[mi], bfv[ni],
                                                              acc[mi][ni], 0, 0, 0);
    __syncthreads();
  }
#pragma unroll
  for (int mi = 0; mi < MT; mi++) {
#pragma unroll
    for (int ni = 0; ni < NT; ni++) {
      int row_base = m0 + wm + mi * 16 + quad * 4;
      int col = n0 + wn + ni * 16 + l16;
#pragma unroll
      for (int r = 0; r < 4; r++) {
        if (MODE == 1) {
          ((ushort_t*)Cv)[(size_t)(row_base + r) * ldc + col] = f2bf(acc[mi][ni][r]);
        } else {
          float* cp = (float*)Cv + (size_t)(row_base + r) * ldc + col;
          float val = acc[mi][ni][r];
          if (MODE == 2) val += *cp;
          *cp = val;
        }
      }
    }
  }
}

// ---------------------------------------------------------------------------
// 256x256 pipelined GEMM (T2 swizzle + T4 counted-vmcnt + T5 setprio + T1).
// BK=32, 512 threads = 8 waves (2M x 4N), per-wave 128x64 output (acc[8][4]).
// LDS: 4-slot ring of (A 16KB + B 16KB) = 128 KiB, depth-3 prefetch,
// steady-state s_waitcnt vmcnt(12) (never 0 in main loop; peeled 8/4/0 tail).
// MODE 0: bf16 store (C[ldc]); MODE 1: fused LSE epilogue (LM head).
// ---------------------------------------------------------------------------
#define GBODY(T, VMSTR, DOSTAGE)                                              \
  {                                                                           \
    if (DOSTAGE) STAGE((T) + 3);                                              \
    asm volatile("s_waitcnt vmcnt(" VMSTR ")" ::: "memory");                  \
    __builtin_amdgcn_sched_barrier(0);                                        \
    __builtin_amdgcn_s_barrier();                                             \
    __builtin_amdgcn_sched_barrier(0);                                        \
    asm volatile("" ::: "memory");                                            \
    const ushort_t* bA = smem + ((T) & 3) * 16384;                            \
    const ushort_t* bB = bA + 8192;                                           \
    short8 af[8], bfv[4];                                                     \
    _Pragma("unroll") for (int mi = 0; mi < 8; mi++) {                        \
      int row = wm + mi * 16 + l16;                                           \
      af[mi] = *(const short8*)(bA + row * 32 + ((quad ^ ((row >> 1) & 3)) << 3)); \
    }                                                                         \
    _Pragma("unroll") for (int ni = 0; ni < 4; ni++) {                        \
      int row = wn + ni * 16 + l16;                                           \
      bfv[ni] = *(const short8*)(bB + row * 32 + ((quad ^ ((row >> 1) & 3)) << 3)); \
    }                                                                         \
    __builtin_amdgcn_s_setprio(1);                                            \
    _Pragma("unroll") for (int mi = 0; mi < 8; mi++)                          \
      _Pragma("unroll") for (int ni = 0; ni < 4; ni++)                        \
        acc[mi][ni] = __builtin_amdgcn_mfma_f32_16x16x32_bf16(                \
            af[mi], bfv[ni], acc[mi][ni], 0, 0, 0);                           \
    __builtin_amdgcn_s_setprio(0);                                            \
    __builtin_amdgcn_sched_barrier(0);                                        \
    __builtin_amdgcn_s_barrier();                                             \
    asm volatile("" ::: "memory");                                            \
  }

template <int MODE>
__global__ __launch_bounds__(512, 2) void gemm256_k(
    const ushort_t* __restrict__ A, int lda,
    const ushort_t* __restrict__ B, int ldb,
    void* __restrict__ Cv, int ldc, int K,
    const int* __restrict__ target, float2* __restrict__ partial,
    float* __restrict__ tgt_l, int strip_base) {
  __shared__ __align__(16) ushort_t smem[4 * 16384];  // 128 KiB ring
  int tid = threadIdx.x;
  int wv = tid >> 6, lane = tid & 63, quad = lane >> 4, l16 = lane & 15;
  int wm = (wv >> 2) * 128, wn = (wv & 3) * 64;
  int nwg = gridDim.x * gridDim.y;
  int sw = xcd_swz(blockIdx.x + gridDim.x * blockIdx.y, nwg);
  int bx = sw / gridDim.y, by = sw % gridDim.y;   // y-fastest: share B strip
  int m0 = by * 256, n0 = bx * 256;
  int NT = K / 32;

  floatx4 acc[8][4];
#pragma unroll
  for (int mi = 0; mi < 8; mi++)
#pragma unroll
    for (int ni = 0; ni < 4; ni++) acc[mi][ni] = (floatx4){0.f, 0.f, 0.f, 0.f};

  auto STAGE = [&](int t) {
    int b = t & 3, k0 = t * 32;
    ushort_t* ba = smem + b * 16384;
#pragma unroll
    for (int ra = 0; ra < 2; ra++) {
      int Pb = ra * 8192 + tid * 16;          // byte pos in linear LDS fill
      int row = Pb >> 6;
      int kq = ((Pb >> 4) & 3) ^ ((row >> 1) & 3);   // inverse swizzle on SOURCE
      gl_lds16(A + (size_t)(m0 + row) * lda + k0 + kq * 8,
               ba + ((ra * 8192 + wv * 1024) >> 1));
    }
#pragma unroll
    for (int rb = 0; rb < 2; rb++) {
      int Pb = rb * 8192 + tid * 16;
      int row = Pb >> 6;
      int kq = ((Pb >> 4) & 3) ^ ((row >> 1) & 3);
      gl_lds16(B + (size_t)(n0 + row) * ldb + k0 + kq * 8,
               ba + 8192 + ((rb * 8192 + wv * 1024) >> 1));
    }
  };

  // prologue: fill ring depth 3 (no wait; first GBODY's vmcnt(12) covers t=0)
  STAGE(0);
  STAGE(1);
  STAGE(2);

  for (int t = 0; t < NT - 3; t++) GBODY(t, "12", 1);
  GBODY(NT - 3, "8", 0);
  GBODY(NT - 2, "4", 0);
  GBODY(NT - 1, "0", 0);

  if constexpr (MODE == 0) {
    ushort_t* C = (ushort_t*)Cv;
#pragma unroll
    for (int mi = 0; mi < 8; mi++)
#pragma unroll
      for (int ni = 0; ni < 4; ni++) {
        int rb = m0 + wm + mi * 16 + quad * 4;
        int col = n0 + wn + ni * 16 + l16;
#pragma unroll
        for (int r = 0; r < 4; r++)
          C[(size_t)(rb + r) * ldc + col] = f2bf(acc[mi][ni][r]);
      }
  } else {
    // ---- fused LSE epilogue over this block's 256-col strip ----
    int strip = strip_base + bx;
    int n0g = strip * 256;
    float* pm = (float*)smem;        // [256][4]
    float* pl = pm + 1024;           // [256][4]
    int* tg = (int*)(pl + 1024);     // [256]
    if (tid < 256) tg[tid] = target[m0 + tid];
    __syncthreads();
#pragma unroll
    for (int mi = 0; mi < 8; mi++) {
      float rmax[4], rsum[4];
#pragma unroll
      for (int r = 0; r < 4; r++) {
        float m = acc[mi][0][r];
#pragma unroll
        for (int ni = 1; ni < 4; ni++) m = fmaxf(m, acc[mi][ni][r]);
        rmax[r] = m;
      }
#pragma unroll
      for (int msk = 1; msk <= 8; msk <<= 1)
#pragma unroll
        for (int r = 0; r < 4; r++)
          rmax[r] = fmaxf(rmax[r], __shfl_xor(rmax[r], msk));
#pragma unroll
      for (int r = 0; r < 4; r++) {
        float ssum = 0.f;
#pragma unroll
        for (int ni = 0; ni < 4; ni++) ssum += __expf(acc[mi][ni][r] - rmax[r]);
        rsum[r] = ssum;
      }
#pragma unroll
      for (int msk = 1; msk <= 8; msk <<= 1)
#pragma unroll
        for (int r = 0; r < 4; r++) rsum[r] += __shfl_xor(rsum[r], msk);
      int rib = wm + mi * 16 + quad * 4;
#pragma unroll
      for (int r = 0; r < 4; r++) {
        int tt = tg[rib + r];
#pragma unroll
        for (int ni = 0; ni < 4; ni++) {
          int colg = n0g + wn + ni * 16 + l16;
          if (tt == colg) tgt_l[m0 + rib + r] = acc[mi][ni][r];
        }
      }
      if (l16 == 0) {
#pragma unroll
        for (int r = 0; r < 4; r++) {
          pm[(rib + r) * 4 + (wv & 3)] = rmax[r];
          pl[(rib + r) * 4 + (wv & 3)] = rsum[r];
        }
      }
    }
    __syncthreads();
    if (tid < 256) {
      float m = pm[tid * 4];
#pragma unroll
      for (int j = 1; j < 4; j++) m = fmaxf(m, pm[tid * 4 + j]);
      float l = 0.f;
#pragma unroll
      for (int j = 0; j < 4; j++) l += pl[tid * 4 + j] * __expf(pm[tid * 4 + j] - m);
      partial[(size_t)(m0 + tid) * NSTRIP + strip] = make_float2(m, l);
    }
  }
}

__global__ __launch_bounds__(256) void reduce_lse_k(const float2* __restrict__ partial,
                                                    const int* __restrict__ target,
                                                    const float* __restrict__ tgt_l,
                                                    float* __restrict__ nll) {
  int row = blockIdx.x * 256 + threadIdx.x;
  if (row >= S) return;
  float m = -1e30f, l = 0.f;
  for (int j = 0; j < NSTRIP; j++) {
    float2 pp = partial[(size_t)row * NSTRIP + j];
    float nm = fmaxf(m, pp.x);
    l = l * __expf(m - nm) + pp.y * __expf(pp.x - nm);
    m = nm;
  }
  int t = target[row];
  nll[row] = (t != -100) ? (logf(l) + m - tgt_l[row]) : 0.f;
}

__global__ __launch_bounds__(256) void sum_nll_k(const float* __restrict__ nll,
                                                 float* __restrict__ out) {
  __shared__ float red[256];
  int tid = threadIdx.x;
  float acc = 0.f;
  for (int s = tid; s < S; s += 256) acc += nll[s];
  red[tid] = acc;
  __syncthreads();
  for (int st = 128; st > 0; st >>= 1) {
    if (tid < st) red[tid] += red[tid + st];
    __syncthreads();
  }
  if (tid == 0) out[0] = red[0];
}

// ---------------------------------------------------------------------------
// RoPE cos/sin table (S x 32), computed once per call.
// ---------------------------------------------------------------------------
__global__ __launch_bounds__(256) void rope_tab_k(float2* __restrict__ tab) {
  int idx = blockIdx.x * 256 + threadIdx.x;  // S*32
  int s = idx >> 5, i = idx & 31;
  float invf = expf(-(float)i * (9.210340371976184f / 32.0f));
  float ang = (float)s * invf;
  tab[idx] = make_float2(cosf(ang), sinf(ang));
}

// RoPE in-place on fused qkv buffer (row stride 3072; k at col offset 1024).
__global__ __launch_bounds__(256) void rope_k(ushort_t* __restrict__ qkv,
                                              const float2* __restrict__ tab) {
  int idx = blockIdx.x * 256 + threadIdx.x;   // S*H*32
  int s = idx >> 9;
  int r = idx & 511;
  int hd = r >> 5, i = r & 31;
  float2 cs = tab[(s << 5) | i];
  float c = cs.x, sn = cs.y;
  size_t base = (size_t)s * 3072 + hd * DH + i;
  float q1 = bf2f(qkv[base]), q2 = bf2f(qkv[base + 32]);
  qkv[base] = f2bf(q1 * c - q2 * sn);
  qkv[base + 32] = f2bf(q2 * c + q1 * sn);
  float k1 = bf2f(qkv[base + 1024]), k2 = bf2f(qkv[base + 1024 + 32]);
  qkv[base + 1024] = f2bf(k1 * c - k2 * sn);
  qkv[base + 1024 + 32] = f2bf(k2 * c + k1 * sn);
}

// ---------------------------------------------------------------------------
// Flash attention (MFMA), q/k/v rows stride 3072 (fused qkv), out stride D.
// XCD swizzle: each XCD owns 2 heads (K/V = 1 MB, L2-resident) and runs its
// q-tiles heavy-first (LPT within XCD).
// ---------------------------------------------------------------------------
#define PSTR 72
__global__ __launch_bounds__(256) void flash_attn_k(const ushort_t* __restrict__ q,
                                                    const ushort_t* __restrict__ k,
                                                    const ushort_t* __restrict__ v,
                                                    ushort_t* __restrict__ out) {
  __shared__ __align__(16) ushort_t QPs[64 * PSTR];
  __shared__ __align__(16) ushort_t Ks[64 * PSTR];
  __shared__ __align__(16) ushort_t Vt[64 * PSTR];
  int nwg = gridDim.x * gridDim.y;
  int sw = xcd_swz(blockIdx.x + gridDim.x * blockIdx.y, nwg);
  int hh = sw / gridDim.x;                       // head: 2 per XCD
  int qt = (gridDim.x - 1) - (sw % gridDim.x);   // heavy-first within XCD
  int q0 = qt * 64;
  int tid = threadIdx.x;
  int w = tid >> 6, lane = tid & 63, quad = lane >> 4, l16 = lane & 15;

  {
    int row = tid >> 2, c0 = (tid & 3) * 16;
    const ushort_t* p = q + (size_t)(q0 + row) * 3072 + hh * DH + c0;
    *(int4*)(QPs + row * PSTR + c0) = ((const int4*)p)[0];
    *(int4*)(QPs + row * PSTR + c0 + 8) = ((const int4*)p)[1];
  }
  __syncthreads();
  short8 af[2];
  af[0] = *(const short8*)(QPs + (w * 16 + l16) * PSTR + quad * 8);
  af[1] = *(const short8*)(QPs + (w * 16 + l16) * PSTR + 32 + quad * 8);

  float m_i[4], l_i[4];
  floatx4 oacc[4];
#pragma unroll
  for (int r = 0; r < 4; r++) { m_i[r] = -1e30f; l_i[r] = 0.f; }
#pragma unroll
  for (int ni = 0; ni < 4; ni++) oacc[ni] = (floatx4){0.f, 0.f, 0.f, 0.f};

  for (int kt = 0; kt <= qt; kt++) {
    int kb = kt * 64;
    __syncthreads();
    {
      int row = tid >> 2, c0 = (tid & 3) * 16;
      const ushort_t* p = k + (size_t)(kb + row) * 3072 + hh * DH + c0;
      *(int4*)(Ks + row * PSTR + c0) = ((const int4*)p)[0];
      *(int4*)(Ks + row * PSTR + c0 + 8) = ((const int4*)p)[1];
    }
    {
      const ushort_t* p = v + (size_t)(kb + lane) * 3072 + hh * DH + w * 16;
      ushort_t tmp[16];
      *(int4*)tmp = ((const int4*)p)[0];
      *(int4*)(tmp + 8) = ((const int4*)p)[1];
#pragma unroll
      for (int j = 0; j < 16; j++)
        Vt[(w * 16 + j) * PSTR + lane] = tmp[j];
    }
    __syncthreads();
    floatx4 sfr[4];
#pragma unroll
    for (int ni = 0; ni < 4; ni++) sfr[ni] = (floatx4){0.f, 0.f, 0.f, 0.f};
#pragma unroll
    for (int ks = 0; ks < 2; ks++) {
#pragma unroll
      for (int ni = 0; ni < 4; ni++) {
        short8 bfr = *(const short8*)(Ks + (ni * 16 + l16) * PSTR + ks * 32 + quad * 8);
        sfr[ni] = __builtin_amdgcn_mfma_f32_16x16x32_bf16(af[ks], bfr, sfr[ni], 0, 0, 0);
      }
    }
    int qrow = q0 + w * 16 + quad * 4;
#pragma unroll
    for (int ni = 0; ni < 4; ni++) {
#pragma unroll
      for (int r = 0; r < 4; r++) {
        float s = sfr[ni][r] * 0.125f;
        if (kt == qt) {
          int key = kb + ni * 16 + l16;
          if (key > qrow + r) s = -1e30f;
        }
        sfr[ni][r] = s;
      }
    }
    float tmax[4];
#pragma unroll
    for (int r = 0; r < 4; r++)
      tmax[r] = fmaxf(fmaxf(sfr[0][r], sfr[1][r]), fmaxf(sfr[2][r], sfr[3][r]));
#pragma unroll
    for (int msk = 1; msk <= 8; msk <<= 1)
#pragma unroll
      for (int r = 0; r < 4; r++)
        tmax[r] = fmaxf(tmax[r], __shfl_xor(tmax[r], msk));
    float alpha[4];
#pragma unroll
    for (int r = 0; r < 4; r++) {
      float mn = fmaxf(m_i[r], tmax[r]);
      alpha[r] = __expf(m_i[r] - mn);
      m_i[r] = mn;
    }
    float tsum[4] = {0.f, 0.f, 0.f, 0.f};
#pragma unroll
    for (int ni = 0; ni < 4; ni++) {
#pragma unroll
      for (int r = 0; r < 4; r++) {
        float p = __expf(sfr[ni][r] - m_i[r]);
        sfr[ni][r] = p;
        tsum[r] += p;
      }
    }
#pragma unroll
    for (int msk = 1; msk <= 8; msk <<= 1)
#pragma unroll
      for (int r = 0; r < 4; r++)
        tsum[r] += __shfl_xor(tsum[r], msk);
#pragma unroll
    for (int r = 0; r < 4; r++) l_i[r] = l_i[r] * alpha[r] + tsum[r];
#pragma unroll
    for (int ni = 0; ni < 4; ni++)
#pragma unroll
      for (int r = 0; r < 4; r++) oacc[ni][r] *= alpha[r];
#pragma unroll
    for (int ni = 0; ni < 4; ni++)
#pragma unroll
      for (int r = 0; r < 4; r++)
        QPs[(w * 16 + quad * 4 + r) * PSTR + ni * 16 + l16] = f2bf(sfr[ni][r]);
    __threadfence_block();
#pragma unroll
    for (int ks = 0; ks < 2; ks++) {
      short8 pf = *(const short8*)(QPs + (w * 16 + l16) * PSTR + ks * 32 + quad * 8);
#pragma unroll
      for (int ni = 0; ni < 4; ni++) {
        short8 bfr = *(const short8*)(Vt + (ni * 16 + l16) * PSTR + ks * 32 + quad * 8);
        oacc[ni] = __builtin_amdgcn_mfma_f32_16x16x32_bf16(pf, bfr, oacc[ni], 0, 0, 0);
      }
    }
  }
#pragma unroll
  for (int r = 0; r < 4; r++) l_i[r] = 1.0f / l_i[r];
#pragma unroll
  for (int ni = 0; ni < 4; ni++) {
#pragma unroll
    for (int r = 0; r < 4; r++) {
      int row = q0 + w * 16 + quad * 4 + r;
      out[(size_t)row * D + hh * DH + ni * 16 + l16] = f2bf(oacc[ni][r] * l_i[r]);
    }
  }
}

// ---------------------------------------------------------------------------
__global__ __launch_bounds__(256) void gate_top2_k(const ushort_t* __restrict__ x,
                                                   const float* __restrict__ gw,
                                                   float* __restrict__ comb) {
  int s = blockIdx.x, tid = threadIdx.x;
  __shared__ float xs[D];
  __shared__ float red[E][32];
  __shared__ float lg[E];
  for (int i = tid; i < D; i += 256) xs[i] = bf2f(x[(size_t)s * D + i]);
  __syncthreads();
  int e = tid >> 5, j = tid & 31;
  float p = 0.f;
  for (int d = j; d < D; d += 32) p += xs[d] * gw[e * D + d];
  red[e][j] = p;
  __syncthreads();
  if (tid < E) {
    float sum = 0.f;
    for (int jj = 0; jj < 32; jj++) sum += red[tid][jj];
    lg[tid] = sum;
  }
  __syncthreads();
  if (tid == 0) {
    float m = lg[0];
    for (int i = 1; i < E; i++) m = fmaxf(m, lg[i]);
    float pr[E];
    float ssum = 0.f;
    for (int i = 0; i < E; i++) { pr[i] = __expf(lg[i] - m); ssum += pr[i]; }
    float rs = 1.0f / ssum;
    for (int i = 0; i < E; i++) pr[i] *= rs;
    int b1 = 0;
    for (int i = 1; i < E; i++) if (pr[i] > pr[b1]) b1 = i;
    int b2 = -1;
    for (int i = 0; i < E; i++) {
      if (i == b1) continue;
      if (b2 < 0 || pr[i] > pr[b2]) b2 = i;
    }
    for (int i = 0; i < E; i++)
      comb[(size_t)s * E + i] = (i == b1) ? pr[b1] : ((i == b2) ? pr[b2] : 0.f);
  }
}

// act[s,e,i] = silu(g)*u*comb; gu rows stride 8192 (g cols 0..4095, u 4096..)
__global__ __launch_bounds__(256) void silu_moe_k(const ushort_t* __restrict__ gu,
                                                  const float* __restrict__ comb,
                                                  ushort_t* __restrict__ act) {
  int idx = blockIdx.x * 256 + threadIdx.x;   // S*4096
  int s = idx >> 12, rem = idx & 4095;
  int e = rem >> 9;
  size_t gi = (size_t)s * 8192 + rem;
  float gv = bf2f(gu[gi]);
  float sig = 1.0f / (1.0f + __expf(-gv));
  act[idx] = f2bf(gv * sig * bf2f(gu[gi + 4096]) * comb[(size_t)s * E + e]);
}

// xgu rows stride 2048: cols 0..1023 = sg result, 1024.. = su result.
// In-place: xgu[s][i] = silu(xgu[s][i]) * xgu[s][1024+i]
__global__ __launch_bounds__(256) void silu2_k(ushort_t* __restrict__ xgu) {
  int idx = blockIdx.x * 256 + threadIdx.x;   // S*SI
  int s = idx >> 10, i = idx & 1023;
  size_t a = (size_t)s * 2048 + i;
  float av = bf2f(xgu[a]);
  float sig = 1.0f / (1.0f + __expf(-av));
  xgu[a] = f2bf(av * sig * bf2f(xgu[a + 1024]));
}

// ---------------------------------------------------------------------------
extern "C" void kernel_launch(void* const* d_in, const int* in_sizes, int n_in,
                              void* d_out, int out_size, void* d_ws, size_t ws_size,
                              hipStream_t stream) {
  const int* src_tokens   = (const int*)d_in[0];
  const int* target       = (const int*)d_in[1];
  const float* embed      = (const float*)d_in[2];
  const float* Wq         = (const float*)d_in[3];
  const float* Wk         = (const float*)d_in[4];
  const float* Wv         = (const float*)d_in[5];
  const float* Wo         = (const float*)d_in[6];
  const float* ln1        = (const float*)d_in[7];
  const float* ln2        = (const float*)d_in[8];
  const float* gate_w     = (const float*)d_in[9];
  const float* gate_projs = (const float*)d_in[10];
  const float* up_projs   = (const float*)d_in[11];
  const float* down_projs = (const float*)d_in[12];
  const float* sg         = (const float*)d_in[13];
  const float* su         = (const float*)d_in[14];
  const float* sd         = (const float*)d_in[15];
  const float* final_ln   = (const float*)d_in[16];
  const float* lm_head    = (const float*)d_in[17];
  float* out = (float*)d_out;

  // ---- workspace carve (~171 MB) ----
  const size_t SD = (size_t)S * D;
  char* p = (char*)d_ws;
  float* h        = (float*)p;    p += SD * 4;                       // 8 MB
  ushort_t* qkvb  = (ushort_t*)p; p += (size_t)S * 3072 * 2;         // 12 MB
  ushort_t* xb    = (ushort_t*)p; p += SD * 2;                       // 4 MB
  ushort_t* aob   = (ushort_t*)p; p += SD * 2;                       // 4 MB
  ushort_t* gu    = (ushort_t*)p; p += (size_t)S * 8192 * 2;         // 33.5 MB
  ushort_t* act_bf= (ushort_t*)p; p += (size_t)S * 4096 * 2;         // 16.8 MB
  ushort_t* xgu   = (ushort_t*)p; p += (size_t)S * 2048 * 2;         // 8.4 MB
  float* comb     = (float*)p;    p += (size_t)S * E * 4;
  float* tgt_l    = (float*)p;    p += S * 4;
  float* nll      = (float*)p;    p += S * 4;
  float2* partial = (float2*)p;   p += (size_t)S * NSTRIP * 8;       // 2 MB
  float2* rtab    = (float2*)p;   p += (size_t)S * 32 * 8;           // 0.5 MB
  ushort_t* qkv_w = (ushort_t*)p; p += (size_t)LAYERS * 3072 * D * 2;
  ushort_t* Wo_bf = (ushort_t*)p; p += (size_t)LAYERS * D * D * 2;
  ushort_t* gu_w  = (ushort_t*)p; p += (size_t)LAYERS * 8192 * D * 2;
  ushort_t* dp_bf = (ushort_t*)p; p += (size_t)LAYERS * E * D * I_DIM * 2;
  ushort_t* sgsu_w= (ushort_t*)p; p += (size_t)LAYERS * 2048 * D * 2;
  ushort_t* sd_bf = (ushort_t*)p; p += (size_t)LAYERS * D * SI * 2;
  ushort_t* lmc   = gu;  // lm chunk (<=33.6 MB) aliases gu+act (dead in lm phase)

  auto conv = [&](const float* src, ushort_t* dst, size_t n) {
    convert_k<<<(int)(n / 8 / 256), 256, 0, stream>>>(src, dst, (int)(n / 8));
  };
  const size_t DD = (size_t)D * D;
  for (int l = 0; l < LAYERS; l++) {
    conv(Wq + l * DD, qkv_w + (size_t)l * 3072 * D, DD);
    conv(Wk + l * DD, qkv_w + (size_t)l * 3072 * D + 1024 * D, DD);
    conv(Wv + l * DD, qkv_w + (size_t)l * 3072 * D + 2048 * D, DD);
    conv(gate_projs + (size_t)l * 4096 * D, gu_w + (size_t)l * 8192 * D, 4096 * (size_t)D);
    conv(up_projs + (size_t)l * 4096 * D, gu_w + (size_t)l * 8192 * D + 4096 * D, 4096 * (size_t)D);
    conv(sg + l * (size_t)SI * D, sgsu_w + (size_t)l * 2048 * D, (size_t)SI * D);
    conv(su + l * (size_t)SI * D, sgsu_w + (size_t)l * 2048 * D + 1024 * D, (size_t)SI * D);
  }
  conv(Wo, Wo_bf, LAYERS * DD);
  conv(down_projs, dp_bf, (size_t)LAYERS * E * D * I_DIM);
  conv(sd, sd_bf, (size_t)LAYERS * D * SI);

  rope_tab_k<<<(S * 32) / 256, 256, 0, stream>>>(rtab);
  embed_k<<<(S * D / 4) / 256, 256, 0, stream>>>(src_tokens, embed, h);

  for (int l = 0; l < LAYERS; l++) {
    rmsnorm_k<<<S, 256, 0, stream>>>(h, ln1 + (size_t)l * D, xb);
    // fused QKV: N=3072, 128x128 tiles (16 MFMA/barrier), grid 24x16=384
    gbt_k<128, 128, 1, 0><<<dim3(3072 / 128, S / 128), 256, 0, stream>>>(
        xb, D, qkv_w + (size_t)l * 3072 * D, D, qkvb, 3072, D);
    rope_k<<<(S * H * 32) / 256, 256, 0, stream>>>(qkvb, rtab);
    flash_attn_k<<<dim3(S / 64, H), 256, 0, stream>>>(qkvb, qkvb + 1024, qkvb + 2048, aob);
    gbt_k<64, 128, 2, 0><<<dim3(D / 128, S / 64), 256, 0, stream>>>(
        aob, D, Wo_bf + (size_t)l * DD, D, h, D, D);

    rmsnorm_k<<<S, 256, 0, stream>>>(h, ln2 + (size_t)l * D, xb);
    gate_top2_k<<<S, 256, 0, stream>>>(xb, gate_w + (size_t)l * E * D, comb);
    // fused gate+up: N=8192, pipelined 256x256 (T1+T2+T4+T5)
    gemm256_k<0><<<dim3(8192 / 256, S / 256), 512, 0, stream>>>(
        xb, D, gu_w + (size_t)l * 8192 * D, D, gu, 8192, D,
        nullptr, nullptr, nullptr, 0);
    silu_moe_k<<<(S * 4096) / 256, 256, 0, stream>>>(gu, comb, act_bf);
    gbt_k<64, 128, 2, 1><<<dim3(D / 128, S / 64), 256, 0, stream>>>(
        act_bf, E * I_DIM, dp_bf + (size_t)l * E * D * I_DIM, 0, h, D, E * I_DIM);
    // fused shared-expert sg+su: N=2048, 128x128 tiles, grid 16x16=256
    gbt_k<128, 128, 1, 0><<<dim3(2048 / 128, S / 128), 256, 0, stream>>>(
        xb, D, sgsu_w + (size_t)l * 2048 * D, D, xgu, 2048, D);
    silu2_k<<<(S * SI) / 256, 256, 0, stream>>>(xgu);
    gbt_k<64, 128, 2, 0><<<dim3(D / 128, S / 64), 256, 0, stream>>>(
        xgu, 2048, sd_bf + (size_t)l * D * SI, SI, h, D, SI);
  }

  rmsnorm_k<<<S, 256, 0, stream>>>(h, final_ln, xb);
  // LM head in 2 chunks (64 + 61 strips of 256 cols), fused LSE epilogue,
  // pipelined 256x256 GEMM core.
  {
    conv(lm_head, lmc, (size_t)16384 * D);
    gemm256_k<1><<<dim3(64, S / 256), 512, 0, stream>>>(
        xb, D, lmc, D, nullptr, 0, D, target, partial, tgt_l, 0);
    conv(lm_head + (size_t)16384 * D, lmc, (size_t)15616 * D);
    gemm256_k<1><<<dim3(61, S / 256), 512, 0, stream>>>(
        xb, D, lmc, D, nullptr, 0, D, target, partial, tgt_l, 64);
  }
  reduce_lse_k<<<S / 256, 256, 0, stream>>>(partial, target, tgt_l, nll);
  sum_nll_k<<<1, 256, 0, stream>>>(nll, out);
}

// Round 4
// 1248.226 us; speedup vs baseline: 1.0292x; 1.0292x over previous
//
#include <hip/hip_runtime.h>
#include <hip/hip_bf16.h>

// Problem constants (DeepSeek-V2-style scaled config)
#define S 2048
#define D 1024
#define H 16
#define DH 64
#define LAYERS 2
#define E 8
#define I_DIM 512
#define SI 1024
#define V 32000
#define NSTRIP 125   // V / 256

typedef unsigned short ushort_t;
typedef __attribute__((ext_vector_type(8))) short short8;   // 8 bf16 (4 VGPRs)
typedef __attribute__((ext_vector_type(4))) float floatx4;  // MFMA accumulator

__device__ __forceinline__ float bf2f(ushort_t u) {
  union { unsigned i; float f; } x;
  x.i = ((unsigned)u) << 16;
  return x.f;
}
__device__ __forceinline__ ushort_t f2bf(float f) {
  union { float f; unsigned u; } x; x.f = f;
  unsigned r = x.u + 0x7FFFu + ((x.u >> 16) & 1u);
  return (ushort_t)(r >> 16);
}
__device__ __forceinline__ int pack2(float a, float b) {
  return (int)((unsigned)f2bf(a) | ((unsigned)f2bf(b) << 16));
}

// Bijective XCD-aware block-id swizzle (T1, m204 form).
__device__ __forceinline__ int xcd_swz(int bid, int nwg) {
  int q = nwg >> 3, r = nwg & 7;
  int x = bid & 7, o = bid >> 3;
  return (x < r ? x * (q + 1) : r * (q + 1) + (x - r) * q) + o;
}

// async global->LDS, 16 B per lane; LDS dst = wave-uniform base + lane*16
__device__ __forceinline__ void gl_lds16(const ushort_t* g, ushort_t* l) {
  __builtin_amdgcn_global_load_lds((const __attribute__((address_space(1))) void*)g,
                                   (__attribute__((address_space(3))) void*)l, 16, 0, 0);
}

// ---------------------------------------------------------------------------
__global__ __launch_bounds__(256) void convert_k(const float* __restrict__ in,
                                                 ushort_t* __restrict__ out, int n8) {
  int i = blockIdx.x * 256 + threadIdx.x;
  if (i >= n8) return;
  const float4* p = (const float4*)in + (size_t)i * 2;
  float4 a = p[0], b = p[1];
  int4 pk = {pack2(a.x, a.y), pack2(a.z, a.w), pack2(b.x, b.y), pack2(b.z, b.w)};
  ((int4*)out)[i] = pk;
}

// Row-interleaving convert: src row j (length D) -> dst row 2j+off (stride D).
// Used to pair gate/up (and sg/su) weight rows so the GEMM epilogue can fuse
// silu(g)*u with a lane shuffle (adjacent output cols = g,u of same unit).
__global__ __launch_bounds__(256) void convert_ilv_k(const float* __restrict__ in,
                                                     ushort_t* __restrict__ out,
                                                     int n8, int off) {
  int i = blockIdx.x * 256 + threadIdx.x;
  if (i >= n8) return;
  int row = i >> 7;       // D/8 = 128 groups per row
  int c8 = i & 127;
  const float4* p = (const float4*)in + (size_t)i * 2;
  float4 a = p[0], b = p[1];
  int4 pk = {pack2(a.x, a.y), pack2(a.z, a.w), pack2(b.x, b.y), pack2(b.z, b.w)};
  ((int4*)(out + ((size_t)(2 * row + off)) * D))[c8] = pk;
}

__global__ __launch_bounds__(256) void embed_k(const int* __restrict__ tok,
                                               const float* __restrict__ emb,
                                               float* __restrict__ h) {
  int idx = blockIdx.x * 256 + threadIdx.x;
  if (idx >= S * D / 4) return;
  int s = idx >> 8;
  int d4 = idx & 255;
  int t = tok[s];
  float4 u = *(const float4*)(emb + (size_t)t * D + d4 * 4);
  *(float4*)(h + (size_t)s * D + d4 * 4) = u;
}

__global__ __launch_bounds__(256) void rmsnorm_k(const float* __restrict__ h,
                                                 const float* __restrict__ w,
                                                 ushort_t* __restrict__ xb) {
  int s = blockIdx.x, tid = threadIdx.x;
  __shared__ float red[256];
  float4 hv = *(const float4*)(h + (size_t)s * D + tid * 4);
  red[tid] = hv.x * hv.x + hv.y * hv.y + hv.z * hv.z + hv.w * hv.w;
  __syncthreads();
  for (int st = 128; st > 0; st >>= 1) {
    if (tid < st) red[tid] += red[tid + st];
    __syncthreads();
  }
  float inv = rsqrtf(red[0] * (1.0f / 1024.0f) + 1e-6f);
  float4 wv = *(const float4*)(w + tid * 4);
  int2 pk;
  pk.x = pack2(hv.x * inv * wv.x, hv.y * inv * wv.y);
  pk.y = pack2(hv.z * inv * wv.z, hv.w * inv * wv.w);
  *(int2*)(xb + (size_t)s * D + tid * 4) = pk;
}

// ---------------------------------------------------------------------------
// MFMA GEMM (m97 structure): C[M,N] = A[M,K](bf16) @ B[N,K](bf16)^T
// Tile TM x TN, BK=32, 4 waves (2x2), 16x16x32 bf16 MFMA, async LDS staging.
// MODE 0: f32 store; 1: bf16 store; 2: f32 accumulate;
// MODE 3: fused silu-pair store (B rows interleaved g/u; writes silu(g)*u
//         bf16 at col/2, ldc = half width). EXPERT: B = [E][D][I].
// ---------------------------------------------------------------------------
template <int TM, int TN, int MODE, int EXPERT>
__global__ __launch_bounds__(256) void gbt_k(const ushort_t* __restrict__ A, int lda,
                                             const ushort_t* __restrict__ B, int ldb,
                                             void* __restrict__ Cv, int ldc, int K) {
  constexpr int WM = TM / 2, WN = TN / 2;
  constexpr int MT = WM / 16, NT = WN / 16;
  constexpr int CA = TM / 16, CB = TN / 16;
  __shared__ __align__(16) ushort_t As[TM * 32];
  __shared__ __align__(16) ushort_t Bs[TN * 32];
  int tid = threadIdx.x;
  int nwg = gridDim.x * gridDim.y;
  int sw = xcd_swz(blockIdx.x + gridDim.x * blockIdx.y, nwg);
  int bx = sw / gridDim.y, by = sw % gridDim.y;   // y-fastest: share B panel
  int n0 = bx * TN, m0 = by * TM;
  int w = tid >> 6, lane = tid & 63, quad = lane >> 4, l16 = lane & 15;
  int wm = (w >> 1) * WM, wn = (w & 1) * WN;
  int srow = lane >> 2, sko = (lane & 3) * 8;

  floatx4 acc[MT][NT];
#pragma unroll
  for (int mi = 0; mi < MT; mi++)
#pragma unroll
    for (int ni = 0; ni < NT; ni++)
      acc[mi][ni] = (floatx4){0.f, 0.f, 0.f, 0.f};

  for (int k0 = 0; k0 < K; k0 += 32) {
#pragma unroll
    for (int c = 0; c < CA; c += 4) {
      int ch = c + w;
      const ushort_t* gp = A + (size_t)(m0 + ch * 16 + srow) * lda + k0 + sko;
      gl_lds16(gp, As + ch * 512);
    }
#pragma unroll
    for (int c = 0; c < CB; c += 4) {
      int ch = c + w;
      const ushort_t* gp;
      if (EXPERT) {
        int kk = k0 + sko;
        int e = kk >> 9;
        gp = B + ((size_t)(e * D + n0 + ch * 16 + srow)) * I_DIM + (kk & 511);
      } else {
        gp = B + (size_t)(n0 + ch * 16 + srow) * ldb + k0 + sko;
      }
      gl_lds16(gp, Bs + ch * 512);
    }
    __syncthreads();
    short8 af[MT], bfv[NT];
#pragma unroll
    for (int mi = 0; mi < MT; mi++)
      af[mi] = *(const short8*)(As + (wm + mi * 16 + l16) * 32 + quad * 8);
#pragma unroll
    for (int ni = 0; ni < NT; ni++)
      bfv[ni] = *(const short8*)(Bs + (wn + ni * 16 + l16) * 32 + quad * 8);
#pragma unroll
    for (int mi = 0; mi < MT; mi++)
#pragma unroll
      for (int ni = 0; ni < NT; ni++)
        acc[mi][ni] = __builtin_amdgcn_mfma_f32_16x16x32_bf16(af[mi], bfv[ni],
                                                              acc[mi][ni], 0, 0, 0);
    __syncthreads();
  }
#pragma unroll
  for (int mi = 0; mi < MT; mi++) {
#pragma unroll
    for (int ni = 0; ni < NT; ni++) {
      int row_base = m0 + wm + mi * 16 + quad * 4;
      int col = n0 + wn + ni * 16 + l16;
#pragma unroll
      for (int r = 0; r < 4; r++) {
        if (MODE == 1) {
          ((ushort_t*)Cv)[(size_t)(row_base + r) * ldc + col] = f2bf(acc[mi][ni][r]);
        } else if (MODE == 3) {
          float g = acc[mi][ni][r];
          float u = __shfl_xor(g, 1);
          if (!(l16 & 1)) {
            float sig = 1.0f / (1.0f + __expf(-g));
            ((ushort_t*)Cv)[(size_t)(row_base + r) * ldc + (col >> 1)] =
                f2bf(g * sig * u);
          }
        } else {
          float* cp = (float*)Cv + (size_t)(row_base + r) * ldc + col;
          float val = acc[mi][ni][r];
          if (MODE == 2) val += *cp;
          *cp = val;
        }
      }
    }
  }
}

// ---------------------------------------------------------------------------
// TM2 x 256 pipelined GEMM, 512 threads = 8 waves (2M x 4N), BK=32.
// 2-slot LDS ring (depth-1 prefetch, counted vmcnt never 0 in main loop) so
// 2 blocks/CU co-schedule (m114 overlap) -- the 4-slot/128KiB ring capped
// occupancy at 1 block/CU (R3: MfmaUtil 31%, Occupancy 21%).
// T2 LDS swizzle via pre-swizzled global source + same XOR on read.
// MODE 1: fused LSE epilogue (LM head). MODE 2: fused gate+up silu*comb
// (B rows interleaved g/u), writes act bf16 [*,4096].
// ---------------------------------------------------------------------------
#define GBODY(T, VMSTR, DOSTAGE)                                              \
  {                                                                           \
    if (DOSTAGE) STAGE((T) + 1);                                              \
    asm volatile("s_waitcnt vmcnt(" VMSTR ")" ::: "memory");                  \
    __builtin_amdgcn_sched_barrier(0);                                        \
    __builtin_amdgcn_s_barrier();                                             \
    __builtin_amdgcn_sched_barrier(0);                                        \
    asm volatile("" ::: "memory");                                            \
    const ushort_t* bA = smem + ((T) & 1) * SLOT;                             \
    const ushort_t* bB = bA + TM2 * 32;                                       \
    short8 af[MT], bfv[4];                                                    \
    _Pragma("unroll") for (int mi = 0; mi < MT; mi++) {                       \
      int row = wm + mi * 16 + l16;                                           \
      af[mi] = *(const short8*)(bA + row * 32 + ((quad ^ ((row >> 1) & 3)) << 3)); \
    }                                                                         \
    _Pragma("unroll") for (int ni = 0; ni < 4; ni++) {                        \
      int row = wn + ni * 16 + l16;                                           \
      bfv[ni] = *(const short8*)(bB + row * 32 + ((quad ^ ((row >> 1) & 3)) << 3)); \
    }                                                                         \
    __builtin_amdgcn_s_setprio(1);                                            \
    _Pragma("unroll") for (int mi = 0; mi < MT; mi++)                         \
      _Pragma("unroll") for (int ni = 0; ni < 4; ni++)                        \
        acc[mi][ni] = __builtin_amdgcn_mfma_f32_16x16x32_bf16(                \
            af[mi], bfv[ni], acc[mi][ni], 0, 0, 0);                           \
    __builtin_amdgcn_s_setprio(0);                                            \
    __builtin_amdgcn_sched_barrier(0);                                        \
    __builtin_amdgcn_s_barrier();                                             \
    asm volatile("" ::: "memory");                                            \
  }

template <int TM2, int MODE>
__global__ __launch_bounds__(512, 2) void gemm256_k(
    const ushort_t* __restrict__ A, int lda,
    const ushort_t* __restrict__ B, int ldb,
    void* __restrict__ Cv, int ldc, int K,
    const int* __restrict__ target, float2* __restrict__ partial,
    float* __restrict__ tgt_l, const float* __restrict__ combp, int strip_base) {
  constexpr int MT = TM2 / 32;               // per-wave M fragments
  constexpr int SLOT = (TM2 + 256) * 32;     // shorts per ring slot
  constexpr int RA = TM2 / 128;              // A gl_lds per thread per step
  __shared__ __align__(16) ushort_t smem[2 * SLOT];
  int tid = threadIdx.x;
  int wv = tid >> 6, lane = tid & 63, quad = lane >> 4, l16 = lane & 15;
  int wm = (wv >> 2) * (TM2 / 2), wn = (wv & 3) * 64;
  int nwg = gridDim.x * gridDim.y;
  int sw = xcd_swz(blockIdx.x + gridDim.x * blockIdx.y, nwg);
  int bx = sw / gridDim.y, by = sw % gridDim.y;   // y-fastest: share B strip
  int m0 = by * TM2, n0 = bx * 256;
  int NT = K / 32;

  floatx4 acc[MT][4];
#pragma unroll
  for (int mi = 0; mi < MT; mi++)
#pragma unroll
    for (int ni = 0; ni < 4; ni++) acc[mi][ni] = (floatx4){0.f, 0.f, 0.f, 0.f};

  auto STAGE = [&](int t) {
    int b = t & 1, k0 = t * 32;
    ushort_t* ba = smem + b * SLOT;
#pragma unroll
    for (int ra = 0; ra < RA; ra++) {
      int Pb = ra * 8192 + tid * 16;          // byte pos in linear LDS fill
      int row = Pb >> 6;
      int kq = ((Pb >> 4) & 3) ^ ((row >> 1) & 3);   // inverse swizzle on SOURCE
      gl_lds16(A + (size_t)(m0 + row) * lda + k0 + kq * 8,
               ba + ((ra * 8192 + wv * 1024) >> 1));
    }
#pragma unroll
    for (int rb = 0; rb < 2; rb++) {
      int Pb = rb * 8192 + tid * 16;
      int row = Pb >> 6;
      int kq = ((Pb >> 4) & 3) ^ ((row >> 1) & 3);
      gl_lds16(B + (size_t)(n0 + row) * ldb + k0 + kq * 8,
               ba + TM2 * 32 + ((rb * 8192 + wv * 1024) >> 1));
    }
  };

  // prologue: fill slot 0; depth-1 prefetch thereafter
  STAGE(0);
  if constexpr (RA == 2) {
    for (int t = 0; t < NT - 1; t++) GBODY(t, "4", 1);
    GBODY(NT - 1, "0", 0);
  } else {
    for (int t = 0; t < NT - 1; t++) GBODY(t, "3", 1);
    GBODY(NT - 1, "0", 0);
  }

  if constexpr (MODE == 0) {
    ushort_t* C = (ushort_t*)Cv;
#pragma unroll
    for (int mi = 0; mi < MT; mi++)
#pragma unroll
      for (int ni = 0; ni < 4; ni++) {
        int rb = m0 + wm + mi * 16 + quad * 4;
        int col = n0 + wn + ni * 16 + l16;
#pragma unroll
        for (int r = 0; r < 4; r++)
          C[(size_t)(rb + r) * ldc + col] = f2bf(acc[mi][ni][r]);
      }
  } else if constexpr (MODE == 2) {
    // fused silu(g)*u*comb epilogue; one expert per 256-col tile (e = n0>>10)
    float* cb = (float*)smem;
    int e = n0 >> 10;
    if (tid < TM2) cb[tid] = combp[(size_t)(m0 + tid) * E + e];
    __syncthreads();
    ushort_t* Cp = (ushort_t*)Cv;
#pragma unroll
    for (int mi = 0; mi < MT; mi++)
#pragma unroll
      for (int ni = 0; ni < 4; ni++) {
        int lrow = wm + mi * 16 + quad * 4;
        int colg = n0 + wn + ni * 16 + l16;
#pragma unroll
        for (int r = 0; r < 4; r++) {
          float g = acc[mi][ni][r];
          float u = __shfl_xor(g, 1);
          if (!(l16 & 1)) {
            float sig = 1.0f / (1.0f + __expf(-g));
            Cp[(size_t)(m0 + lrow + r) * 4096 + (colg >> 1)] =
                f2bf(g * sig * u * cb[lrow + r]);
          }
        }
      }
  } else {
    // ---- fused LSE epilogue over this block's 256-col strip ----
    int strip = strip_base + bx;
    int n0g = strip * 256;
    float* pm = (float*)smem;           // [TM2][4]
    float* pl = pm + TM2 * 4;           // [TM2][4]
    int* tg = (int*)(pl + TM2 * 4);     // [TM2]
    if (tid < TM2) tg[tid] = target[m0 + tid];
    __syncthreads();
#pragma unroll
    for (int mi = 0; mi < MT; mi++) {
      float rmax[4], rsum[4];
#pragma unroll
      for (int r = 0; r < 4; r++) {
        float m = acc[mi][0][r];
#pragma unroll
        for (int ni = 1; ni < 4; ni++) m = fmaxf(m, acc[mi][ni][r]);
        rmax[r] = m;
      }
#pragma unroll
      for (int msk = 1; msk <= 8; msk <<= 1)
#pragma unroll
        for (int r = 0; r < 4; r++)
          rmax[r] = fmaxf(rmax[r], __shfl_xor(rmax[r], msk));
#pragma unroll
      for (int r = 0; r < 4; r++) {
        float ssum = 0.f;
#pragma unroll
        for (int ni = 0; ni < 4; ni++) ssum += __expf(acc[mi][ni][r] - rmax[r]);
        rsum[r] = ssum;
      }
#pragma unroll
      for (int msk = 1; msk <= 8; msk <<= 1)
#pragma unroll
        for (int r = 0; r < 4; r++) rsum[r] += __shfl_xor(rsum[r], msk);
      int rib = wm + mi * 16 + quad * 4;
#pragma unroll
      for (int r = 0; r < 4; r++) {
        int tt = tg[rib + r];
#pragma unroll
        for (int ni = 0; ni < 4; ni++) {
          int colg = n0g + wn + ni * 16 + l16;
          if (tt == colg) tgt_l[m0 + rib + r] = acc[mi][ni][r];
        }
      }
      if (l16 == 0) {
#pragma unroll
        for (int r = 0; r < 4; r++) {
          pm[(rib + r) * 4 + (wv & 3)] = rmax[r];
          pl[(rib + r) * 4 + (wv & 3)] = rsum[r];
        }
      }
    }
    __syncthreads();
    if (tid < TM2) {
      float m = pm[tid * 4];
#pragma unroll
      for (int j = 1; j < 4; j++) m = fmaxf(m, pm[tid * 4 + j]);
      float l = 0.f;
#pragma unroll
      for (int j = 0; j < 4; j++) l += pl[tid * 4 + j] * __expf(pm[tid * 4 + j] - m);
      partial[(size_t)(m0 + tid) * NSTRIP + strip] = make_float2(m, l);
    }
  }
}

__global__ __launch_bounds__(256) void reduce_lse_k(const float2* __restrict__ partial,
                                                    const int* __restrict__ target,
                                                    const float* __restrict__ tgt_l,
                                                    float* __restrict__ nll) {
  int row = blockIdx.x * 256 + threadIdx.x;
  if (row >= S) return;
  float m = -1e30f, l = 0.f;
  for (int j = 0; j < NSTRIP; j++) {
    float2 pp = partial[(size_t)row * NSTRIP + j];
    float nm = fmaxf(m, pp.x);
    l = l * __expf(m - nm) + pp.y * __expf(pp.x - nm);
    m = nm;
  }
  int t = target[row];
  nll[row] = (t != -100) ? (logf(l) + m - tgt_l[row]) : 0.f;
}

__global__ __launch_bounds__(256) void sum_nll_k(const float* __restrict__ nll,
                                                 float* __restrict__ out) {
  __shared__ float red[256];
  int tid = threadIdx.x;
  float acc = 0.f;
  for (int s = tid; s < S; s += 256) acc += nll[s];
  red[tid] = acc;
  __syncthreads();
  for (int st = 128; st > 0; st >>= 1) {
    if (tid < st) red[tid] += red[tid + st];
    __syncthreads();
  }
  if (tid == 0) out[0] = red[0];
}

// ---------------------------------------------------------------------------
// RoPE cos/sin table (S x 32), computed once per call.
// ---------------------------------------------------------------------------
__global__ __launch_bounds__(256) void rope_tab_k(float2* __restrict__ tab) {
  int idx = blockIdx.x * 256 + threadIdx.x;  // S*32
  int s = idx >> 5, i = idx & 31;
  float invf = expf(-(float)i * (9.210340371976184f / 32.0f));
  float ang = (float)s * invf;
  tab[idx] = make_float2(cosf(ang), sinf(ang));
}

// RoPE in-place on fused qkv buffer (row stride 3072; k at col offset 1024).
__global__ __launch_bounds__(256) void rope_k(ushort_t* __restrict__ qkv,
                                              const float2* __restrict__ tab) {
  int idx = blockIdx.x * 256 + threadIdx.x;   // S*H*32
  int s = idx >> 9;
  int r = idx & 511;
  int hd = r >> 5, i = r & 31;
  float2 cs = tab[(s << 5) | i];
  float c = cs.x, sn = cs.y;
  size_t base = (size_t)s * 3072 + hd * DH + i;
  float q1 = bf2f(qkv[base]), q2 = bf2f(qkv[base + 32]);
  qkv[base] = f2bf(q1 * c - q2 * sn);
  qkv[base + 32] = f2bf(q2 * c + q1 * sn);
  float k1 = bf2f(qkv[base + 1024]), k2 = bf2f(qkv[base + 1024 + 32]);
  qkv[base + 1024] = f2bf(k1 * c - k2 * sn);
  qkv[base + 1024 + 32] = f2bf(k2 * c + k1 * sn);
}

// ---------------------------------------------------------------------------
// Flash attention (MFMA), q/k/v rows stride 3072 (fused qkv), out stride D.
// XCD swizzle: each XCD owns 2 heads (K/V L2-resident), heavy-qt-first (LPT).
// ---------------------------------------------------------------------------
#define PSTR 72
__global__ __launch_bounds__(256) void flash_attn_k(const ushort_t* __restrict__ q,
                                                    const ushort_t* __restrict__ k,
                                                    const ushort_t* __restrict__ v,
                                                    ushort_t* __restrict__ out) {
  __shared__ __align__(16) ushort_t QPs[64 * PSTR];
  __shared__ __align__(16) ushort_t Ks[64 * PSTR];
  __shared__ __align__(16) ushort_t Vt[64 * PSTR];
  int nwg = gridDim.x * gridDim.y;
  int sw = xcd_swz(blockIdx.x + gridDim.x * blockIdx.y, nwg);
  int hh = sw / gridDim.x;                       // head: 2 per XCD
  int qt = (gridDim.x - 1) - (sw % gridDim.x);   // heavy-first within XCD
  int q0 = qt * 64;
  int tid = threadIdx.x;
  int w = tid >> 6, lane = tid & 63, quad = lane >> 4, l16 = lane & 15;

  {
    int row = tid >> 2, c0 = (tid & 3) * 16;
    const ushort_t* p = q + (size_t)(q0 + row) * 3072 + hh * DH + c0;
    *(int4*)(QPs + row * PSTR + c0) = ((const int4*)p)[0];
    *(int4*)(QPs + row * PSTR + c0 + 8) = ((const int4*)p)[1];
  }
  __syncthreads();
  short8 af[2];
  af[0] = *(const short8*)(QPs + (w * 16 + l16) * PSTR + quad * 8);
  af[1] = *(const short8*)(QPs + (w * 16 + l16) * PSTR + 32 + quad * 8);

  float m_i[4], l_i[4];
  floatx4 oacc[4];
#pragma unroll
  for (int r = 0; r < 4; r++) { m_i[r] = -1e30f; l_i[r] = 0.f; }
#pragma unroll
  for (int ni = 0; ni < 4; ni++) oacc[ni] = (floatx4){0.f, 0.f, 0.f, 0.f};

  for (int kt = 0; kt <= qt; kt++) {
    int kb = kt * 64;
    __syncthreads();
    {
      int row = tid >> 2, c0 = (tid & 3) * 16;
      const ushort_t* p = k + (size_t)(kb + row) * 3072 + hh * DH + c0;
      *(int4*)(Ks + row * PSTR + c0) = ((const int4*)p)[0];
      *(int4*)(Ks + row * PSTR + c0 + 8) = ((const int4*)p)[1];
    }
    {
      const ushort_t* p = v + (size_t)(kb + lane) * 3072 + hh * DH + w * 16;
      ushort_t tmp[16];
      *(int4*)tmp = ((const int4*)p)[0];
      *(int4*)(tmp + 8) = ((const int4*)p)[1];
#pragma unroll
      for (int j = 0; j < 16; j++)
        Vt[(w * 16 + j) * PSTR + lane] = tmp[j];
    }
    __syncthreads();
    floatx4 sfr[4];
#pragma unroll
    for (int ni = 0; ni < 4; ni++) sfr[ni] = (floatx4){0.f, 0.f, 0.f, 0.f};
#pragma unroll
    for (int ks = 0; ks < 2; ks++) {
#pragma unroll
      for (int ni = 0; ni < 4; ni++) {
        short8 bfr = *(const short8*)(Ks + (ni * 16 + l16) * PSTR + ks * 32 + quad * 8);
        sfr[ni] = __builtin_amdgcn_mfma_f32_16x16x32_bf16(af[ks], bfr, sfr[ni], 0, 0, 0);
      }
    }
    int qrow = q0 + w * 16 + quad * 4;
#pragma unroll
    for (int ni = 0; ni < 4; ni++) {
#pragma unroll
      for (int r = 0; r < 4; r++) {
        float s = sfr[ni][r] * 0.125f;
        if (kt == qt) {
          int key = kb + ni * 16 + l16;
          if (key > qrow + r) s = -1e30f;
        }
        sfr[ni][r] = s;
      }
    }
    float tmax[4];
#pragma unroll
    for (int r = 0; r < 4; r++)
      tmax[r] = fmaxf(fmaxf(sfr[0][r], sfr[1][r]), fmaxf(sfr[2][r], sfr[3][r]));
#pragma unroll
    for (int msk = 1; msk <= 8; msk <<= 1)
#pragma unroll
      for (int r = 0; r < 4; r++)
        tmax[r] = fmaxf(tmax[r], __shfl_xor(tmax[r], msk));
    float alpha[4];
#pragma unroll
    for (int r = 0; r < 4; r++) {
      float mn = fmaxf(m_i[r], tmax[r]);
      alpha[r] = __expf(m_i[r] - mn);
      m_i[r] = mn;
    }
    float tsum[4] = {0.f, 0.f, 0.f, 0.f};
#pragma unroll
    for (int ni = 0; ni < 4; ni++) {
#pragma unroll
      for (int r = 0; r < 4; r++) {
        float p = __expf(sfr[ni][r] - m_i[r]);
        sfr[ni][r] = p;
        tsum[r] += p;
      }
    }
#pragma unroll
    for (int msk = 1; msk <= 8; msk <<= 1)
#pragma unroll
      for (int r = 0; r < 4; r++)
        tsum[r] += __shfl_xor(tsum[r], msk);
#pragma unroll
    for (int r = 0; r < 4; r++) l_i[r] = l_i[r] * alpha[r] + tsum[r];
#pragma unroll
    for (int ni = 0; ni < 4; ni++)
#pragma unroll
      for (int r = 0; r < 4; r++) oacc[ni][r] *= alpha[r];
#pragma unroll
    for (int ni = 0; ni < 4; ni++)
#pragma unroll
      for (int r = 0; r < 4; r++)
        QPs[(w * 16 + quad * 4 + r) * PSTR + ni * 16 + l16] = f2bf(sfr[ni][r]);
    __threadfence_block();
#pragma unroll
    for (int ks = 0; ks < 2; ks++) {
      short8 pf = *(const short8*)(QPs + (w * 16 + l16) * PSTR + ks * 32 + quad * 8);
#pragma unroll
      for (int ni = 0; ni < 4; ni++) {
        short8 bfr = *(const short8*)(Vt + (ni * 16 + l16) * PSTR + ks * 32 + quad * 8);
        oacc[ni] = __builtin_amdgcn_mfma_f32_16x16x32_bf16(pf, bfr, oacc[ni], 0, 0, 0);
      }
    }
  }
#pragma unroll
  for (int r = 0; r < 4; r++) l_i[r] = 1.0f / l_i[r];
#pragma unroll
  for (int ni = 0; ni < 4; ni++) {
#pragma unroll
    for (int r = 0; r < 4; r++) {
      int row = q0 + w * 16 + quad * 4 + r;
      out[(size_t)row * D + hh * DH + ni * 16 + l16] = f2bf(oacc[ni][r] * l_i[r]);
    }
  }
}

// ---------------------------------------------------------------------------
__global__ __launch_bounds__(256) void gate_top2_k(const ushort_t* __restrict__ x,
                                                   const float* __restrict__ gw,
                                                   float* __restrict__ comb) {
  int s = blockIdx.x, tid = threadIdx.x;
  __shared__ float xs[D];
  __shared__ float red[E][32];
  __shared__ float lg[E];
  for (int i = tid; i < D; i += 256) xs[i] = bf2f(x[(size_t)s * D + i]);
  __syncthreads();
  int e = tid >> 5, j = tid & 31;
  float p = 0.f;
  for (int d = j; d < D; d += 32) p += xs[d] * gw[e * D + d];
  red[e][j] = p;
  __syncthreads();
  if (tid < E) {
    float sum = 0.f;
    for (int jj = 0; jj < 32; jj++) sum += red[tid][jj];
    lg[tid] = sum;
  }
  __syncthreads();
  if (tid == 0) {
    float m = lg[0];
    for (int i = 1; i < E; i++) m = fmaxf(m, lg[i]);
    float pr[E];
    float ssum = 0.f;
    for (int i = 0; i < E; i++) { pr[i] = __expf(lg[i] - m); ssum += pr[i]; }
    float rs = 1.0f / ssum;
    for (int i = 0; i < E; i++) pr[i] *= rs;
    int b1 = 0;
    for (int i = 1; i < E; i++) if (pr[i] > pr[b1]) b1 = i;
    int b2 = -1;
    for (int i = 0; i < E; i++) {
      if (i == b1) continue;
      if (b2 < 0 || pr[i] > pr[b2]) b2 = i;
    }
    for (int i = 0; i < E; i++)
      comb[(size_t)s * E + i] = (i == b1) ? pr[b1] : ((i == b2) ? pr[b2] : 0.f);
  }
}

// ---------------------------------------------------------------------------
extern "C" void kernel_launch(void* const* d_in, const int* in_sizes, int n_in,
                              void* d_out, int out_size, void* d_ws, size_t ws_size,
                              hipStream_t stream) {
  const int* src_tokens   = (const int*)d_in[0];
  const int* target       = (const int*)d_in[1];
  const float* embed      = (const float*)d_in[2];
  const float* Wq         = (const float*)d_in[3];
  const float* Wk         = (const float*)d_in[4];
  const float* Wv         = (const float*)d_in[5];
  const float* Wo         = (const float*)d_in[6];
  const float* ln1        = (const float*)d_in[7];
  const float* ln2        = (const float*)d_in[8];
  const float* gate_w     = (const float*)d_in[9];
  const float* gate_projs = (const float*)d_in[10];
  const float* up_projs   = (const float*)d_in[11];
  const float* down_projs = (const float*)d_in[12];
  const float* sg         = (const float*)d_in[13];
  const float* su         = (const float*)d_in[14];
  const float* sd         = (const float*)d_in[15];
  const float* final_ln   = (const float*)d_in[16];
  const float* lm_head    = (const float*)d_in[17];
  float* out = (float*)d_out;

  // ---- workspace carve (~171 MB) ----
  const size_t SD = (size_t)S * D;
  char* p = (char*)d_ws;
  float* h        = (float*)p;    p += SD * 4;                       // 8 MB
  ushort_t* qkvb  = (ushort_t*)p; p += (size_t)S * 3072 * 2;         // 12 MB
  ushort_t* xb    = (ushort_t*)p; p += SD * 2;                       // 4 MB
  ushort_t* aob   = (ushort_t*)p; p += SD * 2;                       // 4 MB
  ushort_t* gu    = (ushort_t*)p; p += (size_t)S * 8192 * 2;         // 33.5 MB
  ushort_t* act_bf= (ushort_t*)p; p += (size_t)S * 4096 * 2;         // 16.8 MB
  ushort_t* xgu   = (ushort_t*)p; p += (size_t)S * 2048 * 2;         // 8.4 MB
  float* comb     = (float*)p;    p += (size_t)S * E * 4;
  float* tgt_l    = (float*)p;    p += S * 4;
  float* nll      = (float*)p;    p += S * 4;
  float2* partial = (float2*)p;   p += (size_t)S * NSTRIP * 8;       // 2 MB
  float2* rtab    = (float2*)p;   p += (size_t)S * 32 * 8;           // 0.5 MB
  ushort_t* qkv_w = (ushort_t*)p; p += (size_t)LAYERS * 3072 * D * 2;
  ushort_t* Wo_bf = (ushort_t*)p; p += (size_t)LAYERS * D * D * 2;
  ushort_t* gu_w  = (ushort_t*)p; p += (size_t)LAYERS * 8192 * D * 2;
  ushort_t* dp_bf = (ushort_t*)p; p += (size_t)LAYERS * E * D * I_DIM * 2;
  ushort_t* sgsu_w= (ushort_t*)p; p += (size_t)LAYERS * 2048 * D * 2;
  ushort_t* sd_bf = (ushort_t*)p; p += (size_t)LAYERS * D * SI * 2;
  ushort_t* lmc   = gu;  // lm chunk (<=33.6 MB) aliases gu (dead in lm phase)

  auto conv = [&](const float* src, ushort_t* dst, size_t n) {
    convert_k<<<(int)(n / 8 / 256), 256, 0, stream>>>(src, dst, (int)(n / 8));
  };
  const size_t DD = (size_t)D * D;
  for (int l = 0; l < LAYERS; l++) {
    conv(Wq + l * DD, qkv_w + (size_t)l * 3072 * D, DD);
    conv(Wk + l * DD, qkv_w + (size_t)l * 3072 * D + 1024 * D, DD);
    conv(Wv + l * DD, qkv_w + (size_t)l * 3072 * D + 2048 * D, DD);
    // interleaved gate/up rows (2j = gate_j, 2j+1 = up_j) for fused-silu epilogue
    convert_ilv_k<<<(4096 * D / 8) / 256, 256, 0, stream>>>(
        gate_projs + (size_t)l * 4096 * D, gu_w + (size_t)l * 8192 * D, 4096 * D / 8, 0);
    convert_ilv_k<<<(4096 * D / 8) / 256, 256, 0, stream>>>(
        up_projs + (size_t)l * 4096 * D, gu_w + (size_t)l * 8192 * D, 4096 * D / 8, 1);
    // interleaved sg/su rows
    convert_ilv_k<<<(1024 * D / 8) / 256, 256, 0, stream>>>(
        sg + (size_t)l * SI * D, sgsu_w + (size_t)l * 2048 * D, 1024 * D / 8, 0);
    convert_ilv_k<<<(1024 * D / 8) / 256, 256, 0, stream>>>(
        su + (size_t)l * SI * D, sgsu_w + (size_t)l * 2048 * D, 1024 * D / 8, 1);
  }
  conv(Wo, Wo_bf, LAYERS * DD);
  conv(down_projs, dp_bf, (size_t)LAYERS * E * D * I_DIM);
  conv(sd, sd_bf, (size_t)LAYERS * D * SI);

  rope_tab_k<<<(S * 32) / 256, 256, 0, stream>>>(rtab);
  embed_k<<<(S * D / 4) / 256, 256, 0, stream>>>(src_tokens, embed, h);

  for (int l = 0; l < LAYERS; l++) {
    rmsnorm_k<<<S, 256, 0, stream>>>(h, ln1 + (size_t)l * D, xb);
    // fused QKV: N=3072, 128x128 tiles
    gbt_k<128, 128, 1, 0><<<dim3(3072 / 128, S / 128), 256, 0, stream>>>(
        xb, D, qkv_w + (size_t)l * 3072 * D, D, qkvb, 3072, D);
    rope_k<<<(S * H * 32) / 256, 256, 0, stream>>>(qkvb, rtab);
    flash_attn_k<<<dim3(S / 64, H), 256, 0, stream>>>(qkvb, qkvb + 1024, qkvb + 2048, aob);
    gbt_k<64, 128, 2, 0><<<dim3(D / 128, S / 64), 256, 0, stream>>>(
        aob, D, Wo_bf + (size_t)l * DD, D, h, D, D);

    rmsnorm_k<<<S, 256, 0, stream>>>(h, ln2 + (size_t)l * D, xb);
    gate_top2_k<<<S, 256, 0, stream>>>(xb, gate_w + (size_t)l * E * D, comb);
    // fused gate+up+silu*comb: N=8192 interleaved, 128x256 tiles, 512 blocks
    gemm256_k<128, 2><<<dim3(8192 / 256, S / 128), 512, 0, stream>>>(
        xb, D, gu_w + (size_t)l * 8192 * D, D, act_bf, 4096, D,
        nullptr, nullptr, nullptr, comb, 0);
    gbt_k<64, 128, 2, 1><<<dim3(D / 128, S / 64), 256, 0, stream>>>(
        act_bf, E * I_DIM, dp_bf + (size_t)l * E * D * I_DIM, 0, h, D, E * I_DIM);
    // fused shared-expert sg+su+silu: N=2048 interleaved -> xgu [S][1024]
    gbt_k<128, 128, 3, 0><<<dim3(2048 / 128, S / 128), 256, 0, stream>>>(
        xb, D, sgsu_w + (size_t)l * 2048 * D, D, xgu, 1024, D);
    gbt_k<64, 128, 2, 0><<<dim3(D / 128, S / 64), 256, 0, stream>>>(
        xgu, 1024, sd_bf + (size_t)l * D * SI, SI, h, D, SI);
  }

  rmsnorm_k<<<S, 256, 0, stream>>>(h, final_ln, xb);
  // LM head in 2 chunks (64 + 61 strips of 256 cols), fused LSE epilogue,
  // 256x256 pipelined core with 2-slot ring (2 blocks/CU).
  {
    conv(lm_head, lmc, (size_t)16384 * D);
    gemm256_k<256, 1><<<dim3(64, S / 256), 512, 0, stream>>>(
        xb, D, lmc, D, nullptr, 0, D, target, partial, tgt_l, nullptr, 0);
    conv(lm_head + (size_t)16384 * D, lmc, (size_t)15616 * D);
    gemm256_k<256, 1><<<dim3(61, S / 256), 512, 0, stream>>>(
        xb, D, lmc, D, nullptr, 0, D, target, partial, tgt_l, nullptr, 64);
  }
  reduce_lse_k<<<S / 256, 256, 0, stream>>>(partial, target, tgt_l, nll);
  sum_nll_k<<<1, 256, 0, stream>>>(nll, out);
}